// Round 14
// baseline (142.501 us; speedup 1.0000x reference)
//
#include <hip/hip_runtime.h>
#include <math.h>

#define BB 32
#define FF 256
#define N1 64
#define N2 256

typedef _Float16 f16;
typedef _Float16 f16x4 __attribute__((ext_vector_type(4)));
typedef _Float16 f16x8 __attribute__((ext_vector_type(8)));
typedef float f32x4 __attribute__((ext_vector_type(4)));

// ---- ws byte offsets ----
#define OFFB_W14T 0u        // 4*256 f32  (W1 cols 0..3, [c][o])
#define OFFB_W1H  45056u    // 256*256 f16 (W1 cols 4..259, [o][k])
#define OFFB_W2H  176128u
#define OFFB_W3H  307200u
#define OFFB_W4H  438272u
#define OFFB_W5H  569344u
#define OFFB_C1G  700416u   // 32*64*256 f16 = 1 MB (c1 per-b staging)

__global__ void k_prep(const float* __restrict__ W1, const float* __restrict__ W2,
                       const float* __restrict__ W3, const float* __restrict__ W4,
                       const float* __restrict__ W5, char* __restrict__ wsb) {
  int x = blockIdx.x, m = blockIdx.y, t = threadIdx.x;
  int idx = x * 256 + t;
  if (m == 0)      ((f16*)(wsb + OFFB_W2H))[idx] = (f16)W2[idx];
  else if (m == 1) ((f16*)(wsb + OFFB_W3H))[idx] = (f16)W3[idx];
  else if (m == 2) ((f16*)(wsb + OFFB_W4H))[idx] = (f16)W4[idx];
  else if (m == 3) ((f16*)(wsb + OFFB_W5H))[idx] = (f16)W5[idx];
  else if (m == 4) ((f16*)(wsb + OFFB_W1H))[idx] = (f16)W1[x * 260 + 4 + t];
  else if (x < 4)  ((float*)(wsb + OFFB_W14T))[x * 256 + t] = W1[t * 260 + x];
}

// Fragment-ordered layouts (verified R3-R13):
// 32m x 256k tile: frag(ks,mf) at (ks*2+mf)*1024, lane L at +L*16 (b128, no-conflict)
// 64n x 256f t-tile: frag((f>>5)*4 + (n>>4))*1024.

#define ZERO_ACC                                                  \
  _Pragma("unroll") for (int of = 0; of < 2; ++of)                \
  _Pragma("unroll") for (int mf = 0; mf < 2; ++mf)                \
      acc[of][mf] = (f32x4){0.f, 0.f, 0.f, 0.f};

// o-range 32 GEMM, depth-1 rolling prefetch + setprio (R6/R13 form).
#define GEMM2(SRC)                                                                \
  {                                                                               \
    f16x8 bfa0 = *(const f16x8*)((SRC) + 0 * 1024 + lane * 16);                   \
    f16x8 bfa1 = *(const f16x8*)((SRC) + 1 * 1024 + lane * 16);                   \
    __builtin_amdgcn_s_setprio(1);                                                \
    _Pragma("unroll") for (int ks = 0; ks < 8; ++ks) {                            \
      f16x8 bfb0 = bfa0, bfb1 = bfa1;                                             \
      if (ks < 7) {                                                               \
        bfb0 = *(const f16x8*)((SRC) + ((ks + 1) * 2 + 0) * 1024 + lane * 16);    \
        bfb1 = *(const f16x8*)((SRC) + ((ks + 1) * 2 + 1) * 1024 + lane * 16);    \
      }                                                                           \
      _Pragma("unroll") for (int of = 0; of < 2; ++of) {                          \
        acc[of][0] = __builtin_amdgcn_mfma_f32_16x16x32_f16(wreg[of][ks], bfa0,   \
                                                            acc[of][0], 0, 0, 0); \
        acc[of][1] = __builtin_amdgcn_mfma_f32_16x16x32_f16(wreg[of][ks], bfa1,   \
                                                            acc[of][1], 0, 0, 0); \
      }                                                                           \
      bfa0 = bfb0; bfa1 = bfb1;                                                   \
    }                                                                             \
    __builtin_amdgcn_s_setprio(0);                                                \
  }

// wreg from f16 ws copies (single f16x8 loads, no conversion temps)
#define LOAD_WREG(WH)                                                             \
  _Pragma("unroll") for (int of = 0; of < 2; ++of)                                \
  _Pragma("unroll") for (int ks = 0; ks < 8; ++ks)                                \
      wreg[of][ks] = *(const f16x8*)((WH) + (wg * 32 + of * 16 + r) * 256 +       \
                                     ks * 32 + g * 8);

// bias read from LDS at use (short live range), relu+cvt, frag store
#define STORE_FRAG(DST, BIASP)                                                    \
  _Pragma("unroll") for (int of = 0; of < 2; ++of) {                              \
    f32x4 bv = *(const f32x4*)((BIASP) + wg * 32 + of * 16 + g * 4);              \
    _Pragma("unroll") for (int mf = 0; mf < 2; ++mf) {                            \
      f16x4 hv;                                                                   \
      _Pragma("unroll") for (int j = 0; j < 4; ++j)                               \
          hv[j] = (f16)fmaxf(acc[of][mf][j] + bv[j], 0.f);                        \
      *(f16x4*)((DST) + (wg * 2 + mf) * 1024 + (of * 2 + (g >> 1)) * 256 +        \
                r * 16 + (g & 1) * 8) = hv;                                       \
    }                                                                             \
  }

#define POOLUP(BIASP)                                                             \
  _Pragma("unroll") for (int of = 0; of < 2; ++of) {                              \
    f32x4 bv = *(const f32x4*)((BIASP) + wg * 32 + of * 16 + g * 4);              \
    _Pragma("unroll") for (int mf = 0; mf < 2; ++mf)                              \
    _Pragma("unroll") for (int j = 0; j < 4; ++j) {                               \
      f16 hv = (f16)fmaxf(acc[of][mf][j] + bv[j], 0.f);                           \
      if (hv > pool[of][mf][j]) pool[of][mf][j] = hv;                             \
    }                                                                             \
  }

// wave w produces y1 frag (ks=kp, mf=mp) for row NN from preloaded C8 (global).
#define PRODUCE_ROW(NN, C8)                                                       \
  {                                                                               \
    float simv = sml[(NN) * 32 + mp * 16 + r];                                    \
    f16x8 h;                                                                      \
    _Pragma("unroll") for (int q = 0; q < 4; ++q) {                               \
      h[q] = (f16)fmaxf(fmaf(w1a[q], simv, (float)(C8)[q]), 0.f);                 \
      h[4 + q] = (f16)fmaxf(fmaf(w1b[q], simv, (float)(C8)[4 + q]), 0.f);         \
    }                                                                             \
    *(f16x8*)(Y1S(NN) + w * 1024 + lane * 16) = h;                                \
  }

// 16 waves: A=0-7 (L2/L4), B=8-15 (L3+pool/L5). o-split 32, 4 waves/SIMD.
// 2-row phases (1 barrier per 2 rows), 4-slot y1/y2 rings, c1 in global ws.
__global__ __launch_bounds__(1024, 4) void k_mega(
    const float* __restrict__ sf, const float* __restrict__ tf,
    const float* __restrict__ seeds, const float* __restrict__ b1,
    const float* __restrict__ b2, const float* __restrict__ b3,
    const float* __restrict__ b4, const float* __restrict__ b5,
    char* __restrict__ wsb, float* __restrict__ out) {
  const int mt = blockIdx.x, b = blockIdx.y, mb = mt * 32;
  const int tid = threadIdx.x;
  const int w = tid >> 6, lane = tid & 63, g = lane >> 4, r = lane & 15;
  const int grp = w >> 3, wg = w & 7;
  const int kp = w >> 1, mp = w & 1;

  const float* w14t = (const float*)(wsb + OFFB_W14T);
  const f16* w1h = (const f16*)(wsb + OFFB_W1H);
  const f16* w2h = (const f16*)(wsb + OFFB_W2H);
  const f16* w3h = (const f16*)(wsb + OFFB_W3H);
  const f16* w4h = (const f16*)(wsb + OFFB_W4H);
  const f16* w5h = (const f16*)(wsb + OFFB_W5H);
  f16* c1b = (f16*)(wsb + OFFB_C1G) + (size_t)b * 16384;  // [n][o] f16

  // LDS arena: y1 ring4 [0,64K) | y2 ring4 [64K,128K) | sml | blds | invt/invs
  __shared__ __align__(16) char arena[143744];
#define Y1S(n) (arena + ((n) & 3) * 16384)
#define Y2S(n) (arena + 65536 + ((n) & 3) * 16384)
  float* sml = (float*)(arena + 131072);       // 64*32 f32 = 8192
  float* blds = (float*)(arena + 139264);      // 4*256 f32 = 4096
  float* invt_l = (float*)(arena + 143360);    // 64 f32
  float* invs_l = (float*)(arena + 143616);    // 32 f32
  // prologue-only partials: alias y2 slots 2,3 (first written at rows 2,3)
  float* part_t = (float*)(arena + 98304);     // 64*16 f32
  float* part_s = (float*)(arena + 102400);    // 32*32 f32

  // ---- t-tile: load f32, ssq partial, cvt f16, store frags (y1 slots 0,1)
  {
    const int n = tid & 63, fo = tid >> 6;
    float ssq = 0.f;
#pragma unroll
    for (int j = 0; j < 2; ++j) {
      int oct = j * 16 + fo;
      f16x8 h;
#pragma unroll
      for (int e = 0; e < 8; ++e) {
        float v = tf[((size_t)b * FF + oct * 8 + e) * N1 + n];
        ssq = fmaf(v, v, ssq);
        h[e] = (f16)v;
      }
      *(f16x8*)(arena + ((oct >> 2) * 4 + (n >> 4)) * 1024 +
                ((oct & 3) * 16 + (n & 15)) * 16) = h;
    }
    part_t[n * 16 + fo] = ssq;
  }
  // ---- s-tile: load f32, ssq partial, store RAW f16 frags (y2 slot 0)
  {
    const int m = tid & 31, q = tid >> 5;
    float ssq = 0.f;
    f16x8 h;
#pragma unroll
    for (int e = 0; e < 8; ++e) {
      float v = sf[((size_t)b * FF + q * 8 + e) * N2 + mb + m];
      ssq = fmaf(v, v, ssq);
      h[e] = (f16)v;
    }
    *(f16x8*)(arena + 65536 + ((q >> 2) * 2 + (m >> 4)) * 1024 +
              ((q & 3) * 16 + (m & 15)) * 16) = h;
    part_s[m * 32 + q] = ssq;
  }
  // ---- stage biases into LDS
  if (tid < 256) {
    blds[tid] = b2[tid];
    blds[256 + tid] = b3[tid];
    blds[512 + tid] = b4[tid];
    blds[768 + tid] = b5[tid];
  }
  __syncthreads();
  if (tid < 64) {
    float a = 0.f;
#pragma unroll
    for (int i = 0; i < 16; ++i) a += part_t[tid * 16 + i];
    invt_l[tid] = 1.0f / fmaxf(sqrtf(a), 1e-8f);
  }
  if (tid < 32) {
    float a = 0.f;
#pragma unroll
    for (int i = 0; i < 32; ++i) a += part_s[tid * 32 + i];
    invs_l[tid] = 1.0f / fmaxf(sqrtf(a), 1e-8f);
  }
  __syncthreads();

  // ---- sim-GEMM (waves 0-7): D[n][m] = t^T s_raw, scale invt[n]*invs[m]
  if (w < 8) {
    const int nt = w >> 1, mfs = w & 1;
    f32x4 sa = {0.f, 0.f, 0.f, 0.f};
#pragma unroll
    for (int ks = 0; ks < 8; ++ks) {
      f16x8 af = *(const f16x8*)(arena + (ks * 4 + nt) * 1024 + lane * 16);
      f16x8 bfm = *(const f16x8*)(arena + 65536 + (ks * 2 + mfs) * 1024 + lane * 16);
      sa = __builtin_amdgcn_mfma_f32_16x16x32_f16(af, bfm, sa, 0, 0, 0);
    }
    float ivm = invs_l[mfs * 16 + r];
#pragma unroll
    for (int j = 0; j < 4; ++j) {
      int n = nt * 16 + g * 4 + j;
      sml[n * 32 + mfs * 16 + r] = sa[j] * invt_l[n] * ivm;
    }
  }
  // ---- c1-GEMM (all 16 waves, o-split 16), 2-pass K-split -> GLOBAL c1b
  {
    f32x4 ac[4];
#pragma unroll
    for (int nf = 0; nf < 4; ++nf) ac[nf] = (f32x4){0.f, 0.f, 0.f, 0.f};
#pragma unroll 1
    for (int half = 0; half < 2; ++half) {
      f16x8 w1f[4];
#pragma unroll
      for (int kk = 0; kk < 4; ++kk)
        w1f[kk] = *(const f16x8*)(w1h + (w * 16 + r) * 256 +
                                  (half * 4 + kk) * 32 + g * 8);
#pragma unroll
      for (int kk = 0; kk < 4; ++kk)
#pragma unroll
        for (int nf = 0; nf < 4; ++nf) {
          f16x8 bfm = *(const f16x8*)(arena + ((half * 4 + kk) * 4 + nf) * 1024 +
                                      lane * 16);
          ac[nf] =
              __builtin_amdgcn_mfma_f32_16x16x32_f16(w1f[kk], bfm, ac[nf], 0, 0, 0);
        }
    }
    f32x4 b1v = *(const f32x4*)(b1 + w * 16 + g * 4);
    f32x4 wx = *(const f32x4*)(w14t + 256 + w * 16 + g * 4);
    f32x4 wy = *(const f32x4*)(w14t + 512 + w * 16 + g * 4);
    f32x4 wz = *(const f32x4*)(w14t + 768 + w * 16 + g * 4);
#pragma unroll
    for (int nf = 0; nf < 4; ++nf) {
      int n = nf * 16 + r;
      const float* sd = seeds + ((size_t)b * 64 + n) * 3;
      float sx = sd[0], sy = sd[1], sz = sd[2];
      f16x4 hv;
#pragma unroll
      for (int j = 0; j < 4; ++j)
        hv[j] = (f16)(ac[nf][j] + b1v[j] + wx[j] * sx + wy[j] * sy + wz[j] * sz);
      *(f16x4*)(c1b + n * 256 + w * 16 + g * 4) = hv;
    }
  }
  __syncthreads();   // sml published; c1b in L2; all t/s frag reads done

  // ---- persistent registers (same names both groups)
  f16x8 wreg[2][8];
  f16x4 pool[2][2];
  f32x4 acc[2][2];
  f32x4 w1a, w1b;
  if (grp) { LOAD_WREG(w3h); } else { LOAD_WREG(w2h); }
  w1a = *(const f32x4*)(w14t + kp * 32 + g * 8);
  w1b = *(const f32x4*)(w14t + kp * 32 + g * 8 + 4);
#pragma unroll
  for (int of = 0; of < 2; ++of)
#pragma unroll
    for (int mf = 0; mf < 2; ++mf) pool[of][mf] = (f16x4){0, 0, 0, 0};

  // prologue: produce rows 0,1 (overwrites t staging in y1 slots 0,1)
  {
    f16x8 c80 = *(const f16x8*)(c1b + 0 * 256 + kp * 32 + g * 8);
    f16x8 c81 = *(const f16x8*)(c1b + 1 * 256 + kp * 32 + g * 8);
    PRODUCE_ROW(0, c80);
    PRODUCE_ROW(1, c81);
  }
  __syncthreads();

  const float* bA = blds;          // b2
  const float* bB = blds + 256;    // b3

  // ---- main loop: 32 phases, 1 barrier each; phase p handles rows 2p, 2p+1
  for (int p = 0; p < 32; ++p) {
    const int n0 = 2 * p;
    f16x8 c8a, c8b;
    if (p < 31) {   // issue c1 loads early (L2-hot; hidden under GEMMs)
      c8a = *(const f16x8*)(c1b + (n0 + 2) * 256 + kp * 32 + g * 8);
      c8b = *(const f16x8*)(c1b + (n0 + 3) * 256 + kp * 32 + g * 8);
    }
    if (grp == 0) {
      ZERO_ACC;
      GEMM2(Y1S(n0));
      STORE_FRAG(Y2S(n0), bA);
      ZERO_ACC;
      GEMM2(Y1S(n0 + 1));
      STORE_FRAG(Y2S(n0 + 1), bA);
      if (p < 31) { PRODUCE_ROW(n0 + 2, c8a); PRODUCE_ROW(n0 + 3, c8b); }
    } else {
      if (p > 0) {
        ZERO_ACC;
        GEMM2(Y2S(n0 - 2));
        POOLUP(bB);
        ZERO_ACC;
        GEMM2(Y2S(n0 - 1));
        POOLUP(bB);
      }
      if (p < 31) { PRODUCE_ROW(n0 + 2, c8a); PRODUCE_ROW(n0 + 3, c8b); }
    }
    __syncthreads();
  }

  // ---- tail: B finishes rows 62,63 + writes pooled tile; A loads W4
  if (grp == 1) {
    ZERO_ACC;
    GEMM2(Y2S(62));
    POOLUP(bB);
    ZERO_ACC;
    GEMM2(Y2S(63));
    POOLUP(bB);
#pragma unroll
    for (int of = 0; of < 2; ++of)
#pragma unroll
      for (int mf = 0; mf < 2; ++mf)
        *(f16x4*)(Y1S(0) + (wg * 2 + mf) * 1024 + (of * 2 + (g >> 1)) * 256 +
                  r * 16 + (g & 1) * 8) = pool[of][mf];
  } else {
    LOAD_WREG(w4h);
  }
  __syncthreads();
  // ---- L4 (A); B loads W5
  if (grp == 0) {
    ZERO_ACC;
    GEMM2(Y1S(0));
    STORE_FRAG(Y2S(0), blds + 512);
  } else {
    LOAD_WREG(w5h);
  }
  __syncthreads();
  // ---- L5 (B, no relu) -> out
  if (grp == 1) {
    ZERO_ACC;
    GEMM2(Y2S(0));
#pragma unroll
    for (int of = 0; of < 2; ++of) {
      f32x4 bv = *(const f32x4*)(blds + 768 + wg * 32 + of * 16 + g * 4);
#pragma unroll
      for (int mf = 0; mf < 2; ++mf) {
        float* op = out + ((size_t)(b * 256 + wg * 32 + of * 16 + g * 4)) * 256 +
                    mb + mf * 16 + r;
#pragma unroll
        for (int j = 0; j < 4; ++j)
          op[(size_t)j * 256] = acc[of][mf][j] + bv[j];
      }
    }
  }
}

extern "C" void kernel_launch(void* const* d_in, const int* in_sizes, int n_in,
                              void* d_out, int out_size, void* d_ws, size_t ws_size,
                              hipStream_t stream) {
  const float* sf = (const float*)d_in[0];
  const float* tf = (const float*)d_in[1];
  const float* seeds = (const float*)d_in[2];
  const float* W1 = (const float*)d_in[3];
  const float* b1 = (const float*)d_in[4];
  const float* W2 = (const float*)d_in[5];
  const float* b2 = (const float*)d_in[6];
  const float* W3 = (const float*)d_in[7];
  const float* b3 = (const float*)d_in[8];
  const float* W4 = (const float*)d_in[9];
  const float* b4 = (const float*)d_in[10];
  const float* W5 = (const float*)d_in[11];
  const float* b5 = (const float*)d_in[12];
  char* wsb = (char*)d_ws;
  float* out = (float*)d_out;

  k_prep<<<dim3(256, 6), 256, 0, stream>>>(W1, W2, W3, W4, W5, wsb);
  k_mega<<<dim3(8, BB), 1024, 0, stream>>>(sf, tf, seeds, b1, b2, b3, b4, b5,
                                           wsb, out);
}

// Round 15
// 134.672 us; speedup vs baseline: 1.0581x; 1.0581x over previous
//
#include <hip/hip_runtime.h>
#include <math.h>

#define BB 32
#define FF 256
#define N1 64
#define N2 256

typedef _Float16 f16;
typedef _Float16 f16x4 __attribute__((ext_vector_type(4)));
typedef _Float16 f16x8 __attribute__((ext_vector_type(8)));
typedef float f32x4 __attribute__((ext_vector_type(4)));

// ---- ws byte offsets ----
#define OFFB_W14T 0u        // 4*256 f32  (W1 cols 0..3, [c][o])
#define OFFB_W1H  45056u    // 256*256 f16 (W1 cols 4..259, [o][k])
#define OFFB_W2H  176128u
#define OFFB_W3H  307200u
#define OFFB_W4H  438272u
#define OFFB_W5H  569344u

// Lean prep: 256 blocks, block o converts row o of all five weights.
__global__ void k_prep(const float* __restrict__ W1, const float* __restrict__ W2,
                       const float* __restrict__ W3, const float* __restrict__ W4,
                       const float* __restrict__ W5, char* __restrict__ wsb) {
  int o = blockIdx.x, k = threadIdx.x;
  int idx = o * 256 + k;
  ((f16*)(wsb + OFFB_W2H))[idx] = (f16)W2[idx];
  ((f16*)(wsb + OFFB_W3H))[idx] = (f16)W3[idx];
  ((f16*)(wsb + OFFB_W4H))[idx] = (f16)W4[idx];
  ((f16*)(wsb + OFFB_W5H))[idx] = (f16)W5[idx];
  ((f16*)(wsb + OFFB_W1H))[idx] = (f16)W1[o * 260 + 4 + k];
  if (k < 4) ((float*)(wsb + OFFB_W14T))[k * 256 + o] = W1[o * 260 + k];
}

// Fragment-ordered layouts (verified R3-R14):
// 32m x 256k tile: frag(ks,mf) at (ks*2+mf)*1024, lane L at +L*16 (b128, no-conflict)
// 64n x 256f t-tile: frag((f>>5)*4 + (n>>4))*1024.

#define ZERO_ACC                                                  \
  _Pragma("unroll") for (int of = 0; of < 2; ++of)                \
  _Pragma("unroll") for (int mf = 0; mf < 2; ++mf)                \
      acc[of][mf] = (f32x4){0.f, 0.f, 0.f, 0.f};

// o-range 32 GEMM, depth-1 rolling prefetch + setprio (R6/R13 form).
#define GEMM2(SRC)                                                                \
  {                                                                               \
    f16x8 bfa0 = *(const f16x8*)((SRC) + 0 * 1024 + lane * 16);                   \
    f16x8 bfa1 = *(const f16x8*)((SRC) + 1 * 1024 + lane * 16);                   \
    __builtin_amdgcn_s_setprio(1);                                                \
    _Pragma("unroll") for (int ks = 0; ks < 8; ++ks) {                            \
      f16x8 bfb0 = bfa0, bfb1 = bfa1;                                             \
      if (ks < 7) {                                                               \
        bfb0 = *(const f16x8*)((SRC) + ((ks + 1) * 2 + 0) * 1024 + lane * 16);    \
        bfb1 = *(const f16x8*)((SRC) + ((ks + 1) * 2 + 1) * 1024 + lane * 16);    \
      }                                                                           \
      _Pragma("unroll") for (int of = 0; of < 2; ++of) {                          \
        acc[of][0] = __builtin_amdgcn_mfma_f32_16x16x32_f16(wreg[of][ks], bfa0,   \
                                                            acc[of][0], 0, 0, 0); \
        acc[of][1] = __builtin_amdgcn_mfma_f32_16x16x32_f16(wreg[of][ks], bfa1,   \
                                                            acc[of][1], 0, 0, 0); \
      }                                                                           \
      bfa0 = bfb0; bfa1 = bfb1;                                                   \
    }                                                                             \
    __builtin_amdgcn_s_setprio(0);                                                \
  }

// wreg from f16 ws copies (single f16x8 loads, no conversion temps)
#define LOAD_WREG(WH)                                                             \
  _Pragma("unroll") for (int of = 0; of < 2; ++of)                                \
  _Pragma("unroll") for (int ks = 0; ks < 8; ++ks)                                \
      wreg[of][ks] = *(const f16x8*)((WH) + (wg * 32 + of * 16 + r) * 256 +       \
                                     ks * 32 + g * 8);

// bias read from LDS at use (short live range), relu+cvt, frag store
#define STORE_FRAG(DST, BIASP)                                                    \
  _Pragma("unroll") for (int of = 0; of < 2; ++of) {                              \
    f32x4 bv = *(const f32x4*)((BIASP) + wg * 32 + of * 16 + g * 4);              \
    _Pragma("unroll") for (int mf = 0; mf < 2; ++mf) {                            \
      f16x4 hv;                                                                   \
      _Pragma("unroll") for (int j = 0; j < 4; ++j)                               \
          hv[j] = (f16)fmaxf(acc[of][mf][j] + bv[j], 0.f);                        \
      *(f16x4*)((DST) + (wg * 2 + mf) * 1024 + (of * 2 + (g >> 1)) * 256 +        \
                r * 16 + (g & 1) * 8) = hv;                                       \
    }                                                                             \
  }

#define POOLUP(BIASP)                                                             \
  _Pragma("unroll") for (int of = 0; of < 2; ++of) {                              \
    f32x4 bv = *(const f32x4*)((BIASP) + wg * 32 + of * 16 + g * 4);              \
    _Pragma("unroll") for (int mf = 0; mf < 2; ++mf)                              \
    _Pragma("unroll") for (int j = 0; j < 4; ++j) {                               \
      f16 hv = (f16)fmaxf(acc[of][mf][j] + bv[j], 0.f);                           \
      if (hv > pool[of][mf][j]) pool[of][mf][j] = hv;                             \
    }                                                                             \
  }

// wave w produces y1 frag (ks=w>>1, mf=w&1) for row NN; c1 from LDS.
#define PRODUCE_Y1(NN, DST)                                                       \
  {                                                                               \
    float simv = sml[(NN) * 32 + mp * 16 + r];                                    \
    f16x8 c8 = *(const f16x8*)(c1h + (NN) * 264 + kp * 32 + g * 8);               \
    f16x8 h;                                                                      \
    _Pragma("unroll") for (int q = 0; q < 4; ++q) {                               \
      h[q] = (f16)fmaxf(fmaf(w1a[q], simv, (float)c8[q]), 0.f);                   \
      h[4 + q] = (f16)fmaxf(fmaf(w1b[q], simv, (float)c8[4 + q]), 0.f);           \
    }                                                                             \
    *(f16x8*)((DST) + w * 1024 + lane * 16) = h;                                  \
  }

// 16 waves: A=0-7 (L2/L4), B=8-15 (L3+pool/L5). o-split 32, 4 waves/SIMD.
// Grid (b fastest) -> xcd = b%8: all 8 mt-blocks of a batch share one XCD L2
// (tf slice fetched once per batch instead of 8x).
__global__ __launch_bounds__(1024, 4) void k_mega(
    const float* __restrict__ sf, const float* __restrict__ tf,
    const float* __restrict__ seeds, const float* __restrict__ b1,
    const float* __restrict__ b2, const float* __restrict__ b3,
    const float* __restrict__ b4, const float* __restrict__ b5,
    const char* __restrict__ wsb, float* __restrict__ out) {
  const int mt = blockIdx.y, b = blockIdx.x, mb = mt * 32;
  const int tid = threadIdx.x;
  const int w = tid >> 6, lane = tid & 63, g = lane >> 4, r = lane & 15;
  const int grp = w >> 3, wg = w & 7;
  const int kp = w >> 1, mp = w & 1;

  const float* w14t = (const float*)(wsb + OFFB_W14T);
  const f16* w1h = (const f16*)(wsb + OFFB_W1H);
  const f16* w2h = (const f16*)(wsb + OFFB_W2H);
  const f16* w3h = (const f16*)(wsb + OFFB_W3H);
  const f16* w4h = (const f16*)(wsb + OFFB_W4H);
  const f16* w5h = (const f16*)(wsb + OFFB_W5H);

  // LDS arena: y1 dbuf | y2 dbuf | c1h | sml | biases | invt | invs
  __shared__ __align__(16) char arena[112384];
#define Y1BUF(i) (arena + (i) * 16384)
#define Y2BUF(i) (arena + 32768 + (i) * 16384)
  f16* c1h = (f16*)(arena + 65536);            // 64*264 f16 = 33792 B
  float* sml = (float*)(arena + 99328);        // 64*32 f32 = 8192 B
  float* blds = (float*)(arena + 107520);      // 4*256 f32 = 4096 B
  float* invt_l = (float*)(arena + 111616);    // 64 f32
  float* invs_l = (float*)(arena + 111872);    // 32 f32
  // prologue-only partials: alias y2 buf1 (first y2[1] write is row n=1)
  float* part_t = (float*)(arena + 49152);     // 64*16 f32 = 4 KB
  float* part_s = (float*)(arena + 53248);     // 32*32 f32 = 4 KB

  // ---- t-tile: load f32, ssq partial, cvt f16, store frags — single pass
  {
    const int n = tid & 63, fo = tid >> 6;
    float ssq = 0.f;
#pragma unroll
    for (int j = 0; j < 2; ++j) {
      int oct = j * 16 + fo;
      f16x8 h;
#pragma unroll
      for (int e = 0; e < 8; ++e) {
        float v = tf[((size_t)b * FF + oct * 8 + e) * N1 + n];
        ssq = fmaf(v, v, ssq);
        h[e] = (f16)v;
      }
      *(f16x8*)(arena + ((oct >> 2) * 4 + (n >> 4)) * 1024 +
                ((oct & 3) * 16 + (n & 15)) * 16) = h;
    }
    part_t[n * 16 + fo] = ssq;
  }
  // ---- s-tile: load f32, ssq partial, store RAW f16 frags
  {
    const int m = tid & 31, q = tid >> 5;
    float ssq = 0.f;
    f16x8 h;
#pragma unroll
    for (int e = 0; e < 8; ++e) {
      float v = sf[((size_t)b * FF + q * 8 + e) * N2 + mb + m];
      ssq = fmaf(v, v, ssq);
      h[e] = (f16)v;
    }
    *(f16x8*)(arena + 32768 + ((q >> 2) * 2 + (m >> 4)) * 1024 +
              ((q & 3) * 16 + (m & 15)) * 16) = h;
    part_s[m * 32 + q] = ssq;
  }
  // ---- stage biases into LDS
  if (tid < 256) {
    blds[tid] = b2[tid];
    blds[256 + tid] = b3[tid];
    blds[512 + tid] = b4[tid];
    blds[768 + tid] = b5[tid];
  }
  __syncthreads();
  if (tid < 64) {
    float a = 0.f;
#pragma unroll
    for (int i = 0; i < 16; ++i) a += part_t[tid * 16 + i];
    invt_l[tid] = 1.0f / fmaxf(sqrtf(a), 1e-8f);
  }
  if (tid < 32) {
    float a = 0.f;
#pragma unroll
    for (int i = 0; i < 32; ++i) a += part_s[tid * 32 + i];
    invs_l[tid] = 1.0f / fmaxf(sqrtf(a), 1e-8f);
  }
  __syncthreads();

  // ---- sim-GEMM (waves 0-7): D[n][m] = t^T s_raw, scale invt[n]*invs[m]
  if (w < 8) {
    const int nt = w >> 1, mfs = w & 1;
    f32x4 sa = {0.f, 0.f, 0.f, 0.f};
#pragma unroll
    for (int ks = 0; ks < 8; ++ks) {
      f16x8 af = *(const f16x8*)(arena + (ks * 4 + nt) * 1024 + lane * 16);
      f16x8 bfm = *(const f16x8*)(arena + 32768 + (ks * 2 + mfs) * 1024 + lane * 16);
      sa = __builtin_amdgcn_mfma_f32_16x16x32_f16(af, bfm, sa, 0, 0, 0);
    }
    float ivm = invs_l[mfs * 16 + r];
#pragma unroll
    for (int j = 0; j < 4; ++j) {
      int n = nt * 16 + g * 4 + j;
      sml[n * 32 + mfs * 16 + r] = sa[j] * invt_l[n] * ivm;
    }
  }
  // ---- c1-GEMM (all 16 waves, o-split 16), 2-pass K-split (w1f[4] live)
  {
    f32x4 ac[4];
#pragma unroll
    for (int nf = 0; nf < 4; ++nf) ac[nf] = (f32x4){0.f, 0.f, 0.f, 0.f};
#pragma unroll 1
    for (int half = 0; half < 2; ++half) {
      f16x8 w1f[4];
#pragma unroll
      for (int kk = 0; kk < 4; ++kk)
        w1f[kk] = *(const f16x8*)(w1h + (w * 16 + r) * 256 +
                                  (half * 4 + kk) * 32 + g * 8);
#pragma unroll
      for (int kk = 0; kk < 4; ++kk)
#pragma unroll
        for (int nf = 0; nf < 4; ++nf) {
          f16x8 bfm = *(const f16x8*)(arena + ((half * 4 + kk) * 4 + nf) * 1024 +
                                      lane * 16);
          ac[nf] =
              __builtin_amdgcn_mfma_f32_16x16x32_f16(w1f[kk], bfm, ac[nf], 0, 0, 0);
        }
    }
    // epilogue coefficients AFTER the MFMA loop (short live range)
    f32x4 b1v = *(const f32x4*)(b1 + w * 16 + g * 4);
    f32x4 wx = *(const f32x4*)(w14t + 256 + w * 16 + g * 4);
    f32x4 wy = *(const f32x4*)(w14t + 512 + w * 16 + g * 4);
    f32x4 wz = *(const f32x4*)(w14t + 768 + w * 16 + g * 4);
#pragma unroll
    for (int nf = 0; nf < 4; ++nf) {
      int n = nf * 16 + r;
      const float* sd = seeds + ((size_t)b * 64 + n) * 3;
      float sx = sd[0], sy = sd[1], sz = sd[2];
      f16x4 hv;
#pragma unroll
      for (int j = 0; j < 4; ++j)
        hv[j] = (f16)(ac[nf][j] + b1v[j] + wx[j] * sx + wy[j] * sy + wz[j] * sz);
      *(f16x4*)(c1h + n * 264 + w * 16 + g * 4) = hv;
    }
  }
  __syncthreads();   // sml, c1h published; all t/s frag reads done

  // ---- persistent registers (same names both groups)
  f16x8 wreg[2][8];
  f16x4 pool[2][2];
  f32x4 acc[2][2];
  f32x4 w1a, w1b;
  if (grp) { LOAD_WREG(w3h); } else { LOAD_WREG(w2h); }
  w1a = *(const f32x4*)(w14t + kp * 32 + g * 8);
  w1b = *(const f32x4*)(w14t + kp * 32 + g * 8 + 4);
#pragma unroll
  for (int of = 0; of < 2; ++of)
#pragma unroll
    for (int mf = 0; mf < 2; ++mf) pool[of][mf] = (f16x4){0, 0, 0, 0};

  PRODUCE_Y1(0, Y1BUF(0));   // overwrites t frags (reads done)
  __syncthreads();

  const float* bA = blds;          // b2 for A-group main loop
  const float* bB = blds + 256;    // b3 for B-group main loop

  // ---- main loop (1 barrier/row):
  //   A: GEMM L2(y1[n]) -> store y2[n] -> produce y1[n+1]
  //   B: produce y1[n+1] -> GEMM L3(y2[n-1]) -> pool
  for (int n = 0; n < N1; ++n) {
    if (grp == 0) {
      ZERO_ACC;
      GEMM2(Y1BUF(n & 1));
      STORE_FRAG(Y2BUF(n & 1), bA);
      if (n + 1 < N1) PRODUCE_Y1(n + 1, Y1BUF((n + 1) & 1));
    } else {
      if (n + 1 < N1) PRODUCE_Y1(n + 1, Y1BUF((n + 1) & 1));
      if (n > 0) {
        ZERO_ACC;
        GEMM2(Y2BUF((n - 1) & 1));
        POOLUP(bB);
      }
    }
    __syncthreads();
  }

  // ---- tail: B finishes L3(63) + writes pooled tile; A loads W4
  if (grp == 1) {
    ZERO_ACC;
    GEMM2(Y2BUF(1));
    POOLUP(bB);
#pragma unroll
    for (int of = 0; of < 2; ++of)
#pragma unroll
      for (int mf = 0; mf < 2; ++mf)
        *(f16x4*)(Y1BUF(0) + (wg * 2 + mf) * 1024 + (of * 2 + (g >> 1)) * 256 +
                  r * 16 + (g & 1) * 8) = pool[of][mf];
  } else {
    LOAD_WREG(w4h);
  }
  __syncthreads();
  // ---- L4 (A); B loads W5
  if (grp == 0) {
    ZERO_ACC;
    GEMM2(Y1BUF(0));
    STORE_FRAG(Y2BUF(0), blds + 512);
  } else {
    LOAD_WREG(w5h);
  }
  __syncthreads();
  // ---- L5 (B, no relu) -> out
  if (grp == 1) {
    ZERO_ACC;
    GEMM2(Y2BUF(0));
#pragma unroll
    for (int of = 0; of < 2; ++of) {
      f32x4 bv = *(const f32x4*)(blds + 768 + wg * 32 + of * 16 + g * 4);
#pragma unroll
      for (int mf = 0; mf < 2; ++mf) {
        float* op = out + ((size_t)(b * 256 + wg * 32 + of * 16 + g * 4)) * 256 +
                    mb + mf * 16 + r;
#pragma unroll
        for (int j = 0; j < 4; ++j)
          op[(size_t)j * 256] = acc[of][mf][j] + bv[j];
      }
    }
  }
}

extern "C" void kernel_launch(void* const* d_in, const int* in_sizes, int n_in,
                              void* d_out, int out_size, void* d_ws, size_t ws_size,
                              hipStream_t stream) {
  const float* sf = (const float*)d_in[0];
  const float* tf = (const float*)d_in[1];
  const float* seeds = (const float*)d_in[2];
  const float* W1 = (const float*)d_in[3];
  const float* b1 = (const float*)d_in[4];
  const float* W2 = (const float*)d_in[5];
  const float* b2 = (const float*)d_in[6];
  const float* W3 = (const float*)d_in[7];
  const float* b3 = (const float*)d_in[8];
  const float* W4 = (const float*)d_in[9];
  const float* b4 = (const float*)d_in[10];
  const float* W5 = (const float*)d_in[11];
  const float* b5 = (const float*)d_in[12];
  char* wsb = (char*)d_ws;
  float* out = (float*)d_out;

  k_prep<<<dim3(256), 256, 0, stream>>>(W1, W2, W3, W4, W5, wsb);
  k_mega<<<dim3(BB, 8), 1024, 0, stream>>>(sf, tf, seeds, b1, b2, b3, b4, b5,
                                           wsb, out);
}

// Round 17
// 126.930 us; speedup vs baseline: 1.1227x; 1.0610x over previous
//
#include <hip/hip_runtime.h>
#include <math.h>

#define BB 32
#define FF 256
#define N1 64
#define N2 256

typedef _Float16 f16;
typedef __fp16 h16x2 __attribute__((ext_vector_type(2)));   // cvt_pkrtz result type
typedef _Float16 f16x4 __attribute__((ext_vector_type(4)));
typedef _Float16 f16x8 __attribute__((ext_vector_type(8)));
typedef float f32x4 __attribute__((ext_vector_type(4)));

// ---- ws byte offsets ----
#define OFFB_W14T 0u        // 4*256 f32  (W1 cols 0..3, [c][o])
#define OFFB_W1H  45056u    // 256*256 f16 (W1 cols 4..259, [o][k])
#define OFFB_W2H  176128u
#define OFFB_W3H  307200u
#define OFFB_W4H  438272u
#define OFFB_W5H  569344u

// Lean prep: 256 blocks, block o converts row o of all five weights.
__global__ void k_prep(const float* __restrict__ W1, const float* __restrict__ W2,
                       const float* __restrict__ W3, const float* __restrict__ W4,
                       const float* __restrict__ W5, char* __restrict__ wsb) {
  int o = blockIdx.x, k = threadIdx.x;
  int idx = o * 256 + k;
  ((f16*)(wsb + OFFB_W2H))[idx] = (f16)W2[idx];
  ((f16*)(wsb + OFFB_W3H))[idx] = (f16)W3[idx];
  ((f16*)(wsb + OFFB_W4H))[idx] = (f16)W4[idx];
  ((f16*)(wsb + OFFB_W5H))[idx] = (f16)W5[idx];
  ((f16*)(wsb + OFFB_W1H))[idx] = (f16)W1[o * 260 + 4 + k];
  if (k < 4) ((float*)(wsb + OFFB_W14T))[k * 256 + o] = W1[o * 260 + k];
}

// Fragment-ordered layouts (verified R3-R15):
// 32m x 256k tile: frag(ks,mf) at (ks*2+mf)*1024, lane L at +L*16 (b128, no-conflict)
// 64n x 256f t-tile: frag((f>>5)*4 + (n>>4))*1024.

#define ZERO_ACC                                                  \
  _Pragma("unroll") for (int of = 0; of < 2; ++of)                \
  _Pragma("unroll") for (int mf = 0; mf < 2; ++mf)                \
      acc[of][mf] = (f32x4){0.f, 0.f, 0.f, 0.f};

// o-range 32 GEMM, depth-1 rolling prefetch + setprio (R6/R13 form).
#define GEMM2(SRC)                                                                \
  {                                                                               \
    f16x8 bfa0 = *(const f16x8*)((SRC) + 0 * 1024 + lane * 16);                   \
    f16x8 bfa1 = *(const f16x8*)((SRC) + 1 * 1024 + lane * 16);                   \
    __builtin_amdgcn_s_setprio(1);                                                \
    _Pragma("unroll") for (int ks = 0; ks < 8; ++ks) {                            \
      f16x8 bfb0 = bfa0, bfb1 = bfa1;                                             \
      if (ks < 7) {                                                               \
        bfb0 = *(const f16x8*)((SRC) + ((ks + 1) * 2 + 0) * 1024 + lane * 16);    \
        bfb1 = *(const f16x8*)((SRC) + ((ks + 1) * 2 + 1) * 1024 + lane * 16);    \
      }                                                                           \
      _Pragma("unroll") for (int of = 0; of < 2; ++of) {                          \
        acc[of][0] = __builtin_amdgcn_mfma_f32_16x16x32_f16(wreg[of][ks], bfa0,   \
                                                            acc[of][0], 0, 0, 0); \
        acc[of][1] = __builtin_amdgcn_mfma_f32_16x16x32_f16(wreg[of][ks], bfa1,   \
                                                            acc[of][1], 0, 0, 0); \
      }                                                                           \
      bfa0 = bfb0; bfa1 = bfb1;                                                   \
    }                                                                             \
    __builtin_amdgcn_s_setprio(0);                                                \
  }

// wreg from f16 ws copies (single f16x8 loads, no conversion temps)
#define LOAD_WREG(WH)                                                             \
  _Pragma("unroll") for (int of = 0; of < 2; ++of)                                \
  _Pragma("unroll") for (int ks = 0; ks < 8; ++ks)                                \
      wreg[of][ks] = *(const f16x8*)((WH) + (wg * 32 + of * 16 + r) * 256 +       \
                                     ks * 32 + g * 8);

// relu in f32, packed cvt (v_cvt_pkrtz_f16_f32), b64 frag store
#define STORE_FRAG(DST, BIASP)                                                    \
  _Pragma("unroll") for (int of = 0; of < 2; ++of) {                              \
    f32x4 bv = *(const f32x4*)((BIASP) + wg * 32 + of * 16 + g * 4);              \
    _Pragma("unroll") for (int mf = 0; mf < 2; ++mf) {                            \
      union { h16x2 p[2]; f16x4 v; } u_;                                          \
      u_.p[0] = __builtin_amdgcn_cvt_pkrtz(fmaxf(acc[of][mf][0] + bv[0], 0.f),    \
                                           fmaxf(acc[of][mf][1] + bv[1], 0.f));   \
      u_.p[1] = __builtin_amdgcn_cvt_pkrtz(fmaxf(acc[of][mf][2] + bv[2], 0.f),    \
                                           fmaxf(acc[of][mf][3] + bv[3], 0.f));   \
      *(f16x4*)((DST) + (wg * 2 + mf) * 1024 + (of * 2 + (g >> 1)) * 256 +        \
                r * 16 + (g & 1) * 8) = u_.v;                                     \
    }                                                                             \
  }

// pool >= 0 so max(pool, x) == max(pool, relu(x)): skip relu; packed f16 max.
#define POOLUP(BIASP)                                                             \
  _Pragma("unroll") for (int of = 0; of < 2; ++of) {                              \
    f32x4 bv = *(const f32x4*)((BIASP) + wg * 32 + of * 16 + g * 4);              \
    _Pragma("unroll") for (int mf = 0; mf < 2; ++mf) {                            \
      union { h16x2 p[2]; f16x4 v; } u_;                                          \
      u_.p[0] = __builtin_amdgcn_cvt_pkrtz(acc[of][mf][0] + bv[0],                \
                                           acc[of][mf][1] + bv[1]);               \
      u_.p[1] = __builtin_amdgcn_cvt_pkrtz(acc[of][mf][2] + bv[2],                \
                                           acc[of][mf][3] + bv[3]);               \
      pool[of][mf] = __builtin_elementwise_max(pool[of][mf], u_.v);               \
    }                                                                             \
  }

// wave w produces y1 frag (ks=w>>1, mf=w&1) for row NN; c1 from LDS.
#define PRODUCE_Y1(NN, DST)                                                       \
  {                                                                               \
    float simv = sml[(NN) * 32 + mp * 16 + r];                                    \
    f16x8 c8 = *(const f16x8*)(c1h + (NN) * 264 + kp * 32 + g * 8);               \
    float v_[8];                                                                  \
    _Pragma("unroll") for (int q = 0; q < 4; ++q) {                               \
      v_[q] = fmaxf(fmaf(w1a[q], simv, (float)c8[q]), 0.f);                       \
      v_[4 + q] = fmaxf(fmaf(w1b[q], simv, (float)c8[4 + q]), 0.f);               \
    }                                                                             \
    union { h16x2 p[4]; f16x8 v; } u_;                                            \
    u_.p[0] = __builtin_amdgcn_cvt_pkrtz(v_[0], v_[1]);                           \
    u_.p[1] = __builtin_amdgcn_cvt_pkrtz(v_[2], v_[3]);                           \
    u_.p[2] = __builtin_amdgcn_cvt_pkrtz(v_[4], v_[5]);                           \
    u_.p[3] = __builtin_amdgcn_cvt_pkrtz(v_[6], v_[7]);                           \
    *(f16x8*)((DST) + w * 1024 + lane * 16) = u_.v;                               \
  }

// 16 waves: A=0-7 (L2/L4), B=8-15 (L3+pool/L5). o-split 32, 4 waves/SIMD.
// Grid (b fastest) -> xcd = b%8 (tf slice fetched once per batch).
__global__ __launch_bounds__(1024, 4) void k_mega(
    const float* __restrict__ sf, const float* __restrict__ tf,
    const float* __restrict__ seeds, const float* __restrict__ b1,
    const float* __restrict__ b2, const float* __restrict__ b3,
    const float* __restrict__ b4, const float* __restrict__ b5,
    const char* __restrict__ wsb, float* __restrict__ out) {
  const int mt = blockIdx.y, b = blockIdx.x, mb = mt * 32;
  const int tid = threadIdx.x;
  const int w = tid >> 6, lane = tid & 63, g = lane >> 4, r = lane & 15;
  const int grp = w >> 3, wg = w & 7;
  const int kp = w >> 1, mp = w & 1;

  const float* w14t = (const float*)(wsb + OFFB_W14T);
  const f16* w1h = (const f16*)(wsb + OFFB_W1H);
  const f16* w2h = (const f16*)(wsb + OFFB_W2H);
  const f16* w3h = (const f16*)(wsb + OFFB_W3H);
  const f16* w4h = (const f16*)(wsb + OFFB_W4H);
  const f16* w5h = (const f16*)(wsb + OFFB_W5H);

  // LDS arena: y1 dbuf | y2 dbuf | c1h | sml | biases | invt | invs
  __shared__ __align__(16) char arena[112384];
#define Y1BUF(i) (arena + (i) * 16384)
#define Y2BUF(i) (arena + 32768 + (i) * 16384)
  f16* c1h = (f16*)(arena + 65536);            // 64*264 f16 = 33792 B
  float* sml = (float*)(arena + 99328);        // 64*32 f32 = 8192 B
  float* blds = (float*)(arena + 107520);      // 4*256 f32 = 4096 B
  float* invt_l = (float*)(arena + 111616);    // 64 f32
  float* invs_l = (float*)(arena + 111872);    // 32 f32
  // prologue-only partials: alias y2 buf1 (first y2[1] write is row n=1)
  float* part_t = (float*)(arena + 49152);     // 64*16 f32 = 4 KB
  float* part_s = (float*)(arena + 53248);     // 32*32 f32 = 4 KB

  // ---- t-tile: load f32, ssq partial, cvt f16, store frags — single pass
  {
    const int n = tid & 63, fo = tid >> 6;
    float ssq = 0.f;
#pragma unroll
    for (int j = 0; j < 2; ++j) {
      int oct = j * 16 + fo;
      f16x8 h;
#pragma unroll
      for (int e = 0; e < 8; ++e) {
        float v = tf[((size_t)b * FF + oct * 8 + e) * N1 + n];
        ssq = fmaf(v, v, ssq);
        h[e] = (f16)v;
      }
      *(f16x8*)(arena + ((oct >> 2) * 4 + (n >> 4)) * 1024 +
                ((oct & 3) * 16 + (n & 15)) * 16) = h;
    }
    part_t[n * 16 + fo] = ssq;
  }
  // ---- s-tile: load f32, ssq partial, store RAW f16 frags
  {
    const int m = tid & 31, q = tid >> 5;
    float ssq = 0.f;
    f16x8 h;
#pragma unroll
    for (int e = 0; e < 8; ++e) {
      float v = sf[((size_t)b * FF + q * 8 + e) * N2 + mb + m];
      ssq = fmaf(v, v, ssq);
      h[e] = (f16)v;
    }
    *(f16x8*)(arena + 32768 + ((q >> 2) * 2 + (m >> 4)) * 1024 +
              ((q & 3) * 16 + (m & 15)) * 16) = h;
    part_s[m * 32 + q] = ssq;
  }
  // ---- stage biases into LDS
  if (tid < 256) {
    blds[tid] = b2[tid];
    blds[256 + tid] = b3[tid];
    blds[512 + tid] = b4[tid];
    blds[768 + tid] = b5[tid];
  }
  __syncthreads();
  if (tid < 64) {
    float a = 0.f;
#pragma unroll
    for (int i = 0; i < 16; ++i) a += part_t[tid * 16 + i];
    invt_l[tid] = 1.0f / fmaxf(sqrtf(a), 1e-8f);
  }
  if (tid < 32) {
    float a = 0.f;
#pragma unroll
    for (int i = 0; i < 32; ++i) a += part_s[tid * 32 + i];
    invs_l[tid] = 1.0f / fmaxf(sqrtf(a), 1e-8f);
  }
  __syncthreads();

  // ---- sim-GEMM (waves 0-7): D[n][m] = t^T s_raw, scale invt[n]*invs[m]
  if (w < 8) {
    const int nt = w >> 1, mfs = w & 1;
    f32x4 sa = {0.f, 0.f, 0.f, 0.f};
#pragma unroll
    for (int ks = 0; ks < 8; ++ks) {
      f16x8 af = *(const f16x8*)(arena + (ks * 4 + nt) * 1024 + lane * 16);
      f16x8 bfm = *(const f16x8*)(arena + 32768 + (ks * 2 + mfs) * 1024 + lane * 16);
      sa = __builtin_amdgcn_mfma_f32_16x16x32_f16(af, bfm, sa, 0, 0, 0);
    }
    float ivm = invs_l[mfs * 16 + r];
#pragma unroll
    for (int j = 0; j < 4; ++j) {
      int n = nt * 16 + g * 4 + j;
      sml[n * 32 + mfs * 16 + r] = sa[j] * invt_l[n] * ivm;
    }
  }
  // ---- c1-GEMM (all 16 waves, o-split 16), 2-pass K-split (w1f[4] live)
  {
    f32x4 ac[4];
#pragma unroll
    for (int nf = 0; nf < 4; ++nf) ac[nf] = (f32x4){0.f, 0.f, 0.f, 0.f};
#pragma unroll 1
    for (int half = 0; half < 2; ++half) {
      f16x8 w1f[4];
#pragma unroll
      for (int kk = 0; kk < 4; ++kk)
        w1f[kk] = *(const f16x8*)(w1h + (w * 16 + r) * 256 +
                                  (half * 4 + kk) * 32 + g * 8);
#pragma unroll
      for (int kk = 0; kk < 4; ++kk)
#pragma unroll
        for (int nf = 0; nf < 4; ++nf) {
          f16x8 bfm = *(const f16x8*)(arena + ((half * 4 + kk) * 4 + nf) * 1024 +
                                      lane * 16);
          ac[nf] =
              __builtin_amdgcn_mfma_f32_16x16x32_f16(w1f[kk], bfm, ac[nf], 0, 0, 0);
        }
    }
    // epilogue coefficients AFTER the MFMA loop (short live range)
    f32x4 b1v = *(const f32x4*)(b1 + w * 16 + g * 4);
    f32x4 wx = *(const f32x4*)(w14t + 256 + w * 16 + g * 4);
    f32x4 wy = *(const f32x4*)(w14t + 512 + w * 16 + g * 4);
    f32x4 wz = *(const f32x4*)(w14t + 768 + w * 16 + g * 4);
#pragma unroll
    for (int nf = 0; nf < 4; ++nf) {
      int n = nf * 16 + r;
      const float* sd = seeds + ((size_t)b * 64 + n) * 3;
      float sx = sd[0], sy = sd[1], sz = sd[2];
      f16x4 hv;
#pragma unroll
      for (int j = 0; j < 4; ++j)
        hv[j] = (f16)(ac[nf][j] + b1v[j] + wx[j] * sx + wy[j] * sy + wz[j] * sz);
      *(f16x4*)(c1h + n * 264 + w * 16 + g * 4) = hv;
    }
  }
  __syncthreads();   // sml, c1h published; all t/s frag reads done

  // ---- persistent registers (same names both groups)
  f16x8 wreg[2][8];
  f16x4 pool[2][2];
  f32x4 acc[2][2];
  f32x4 w1a, w1b;
  if (grp) { LOAD_WREG(w3h); } else { LOAD_WREG(w2h); }
  w1a = *(const f32x4*)(w14t + kp * 32 + g * 8);
  w1b = *(const f32x4*)(w14t + kp * 32 + g * 8 + 4);
#pragma unroll
  for (int of = 0; of < 2; ++of)
#pragma unroll
    for (int mf = 0; mf < 2; ++mf) pool[of][mf] = (f16x4){0, 0, 0, 0};

  PRODUCE_Y1(0, Y1BUF(0));   // overwrites t frags (reads done)
  __syncthreads();

  const float* bA = blds;          // b2 for A-group main loop
  const float* bB = blds + 256;    // b3 for B-group main loop

  // ---- main loop (1 barrier/row):
  //   A: GEMM L2(y1[n]) -> store y2[n] -> produce y1[n+1]
  //   B: produce y1[n+1] -> GEMM L3(y2[n-1]) -> pool
  for (int n = 0; n < N1; ++n) {
    if (grp == 0) {
      ZERO_ACC;
      GEMM2(Y1BUF(n & 1));
      STORE_FRAG(Y2BUF(n & 1), bA);
      if (n + 1 < N1) PRODUCE_Y1(n + 1, Y1BUF((n + 1) & 1));
    } else {
      if (n + 1 < N1) PRODUCE_Y1(n + 1, Y1BUF((n + 1) & 1));
      if (n > 0) {
        ZERO_ACC;
        GEMM2(Y2BUF((n - 1) & 1));
        POOLUP(bB);
      }
    }
    __syncthreads();
  }

  // ---- tail: B finishes L3(63) + writes pooled tile; A loads W4
  if (grp == 1) {
    ZERO_ACC;
    GEMM2(Y2BUF(1));
    POOLUP(bB);
#pragma unroll
    for (int of = 0; of < 2; ++of)
#pragma unroll
      for (int mf = 0; mf < 2; ++mf)
        *(f16x4*)(Y1BUF(0) + (wg * 2 + mf) * 1024 + (of * 2 + (g >> 1)) * 256 +
                  r * 16 + (g & 1) * 8) = pool[of][mf];
  } else {
    LOAD_WREG(w4h);
  }
  __syncthreads();
  // ---- L4 (A); B loads W5
  if (grp == 0) {
    ZERO_ACC;
    GEMM2(Y1BUF(0));
    STORE_FRAG(Y2BUF(0), blds + 512);
  } else {
    LOAD_WREG(w5h);
  }
  __syncthreads();
  // ---- L5 (B, no relu) -> out
  if (grp == 1) {
    ZERO_ACC;
    GEMM2(Y2BUF(0));
#pragma unroll
    for (int of = 0; of < 2; ++of) {
      f32x4 bv = *(const f32x4*)(blds + 768 + wg * 32 + of * 16 + g * 4);
#pragma unroll
      for (int mf = 0; mf < 2; ++mf) {
        float* op = out + ((size_t)(b * 256 + wg * 32 + of * 16 + g * 4)) * 256 +
                    mb + mf * 16 + r;
#pragma unroll
        for (int j = 0; j < 4; ++j)
          op[(size_t)j * 256] = acc[of][mf][j] + bv[j];
      }
    }
  }
}

extern "C" void kernel_launch(void* const* d_in, const int* in_sizes, int n_in,
                              void* d_out, int out_size, void* d_ws, size_t ws_size,
                              hipStream_t stream) {
  const float* sf = (const float*)d_in[0];
  const float* tf = (const float*)d_in[1];
  const float* seeds = (const float*)d_in[2];
  const float* W1 = (const float*)d_in[3];
  const float* b1 = (const float*)d_in[4];
  const float* W2 = (const float*)d_in[5];
  const float* b2 = (const float*)d_in[6];
  const float* W3 = (const float*)d_in[7];
  const float* b3 = (const float*)d_in[8];
  const float* W4 = (const float*)d_in[9];
  const float* b4 = (const float*)d_in[10];
  const float* W5 = (const float*)d_in[11];
  const float* b5 = (const float*)d_in[12];
  char* wsb = (char*)d_ws;
  float* out = (float*)d_out;

  k_prep<<<dim3(256), 256, 0, stream>>>(W1, W2, W3, W4, W5, wsb);
  k_mega<<<dim3(BB, 8), 1024, 0, stream>>>(sf, tf, seeds, b1, b2, b3, b4, b5,
                                           wsb, out);
}